// Round 8
// baseline (273.963 us; speedup 1.0000x reference)
//
#include <hip/hip_runtime.h>
#include <hip/hip_bf16.h>

typedef unsigned short u16;
typedef __attribute__((ext_vector_type(8))) short short8;   // 8 bf16 = 4 VGPRs
typedef __attribute__((ext_vector_type(4))) float f32x4;

__device__ __forceinline__ float bf2f(u16 v) {
    union { unsigned u; float f; } c; c.u = ((unsigned)v) << 16; return c.f;
}
__device__ __forceinline__ u16 f2bf(float f) {
    union { float f; unsigned u; } c; c.f = f;
    unsigned r = c.u + 0x7fffu + ((c.u >> 16) & 1u);   // RNE
    return (u16)(r >> 16);
}
__device__ __forceinline__ uint4 pack8(const float4 a, const float4 b) {
    uint4 r;
    r.x = (unsigned)f2bf(a.x) | ((unsigned)f2bf(a.y) << 16);
    r.y = (unsigned)f2bf(a.z) | ((unsigned)f2bf(a.w) << 16);
    r.z = (unsigned)f2bf(b.x) | ((unsigned)f2bf(b.y) << 16);
    r.w = (unsigned)f2bf(b.z) | ((unsigned)f2bf(b.w) << 16);
    return r;
}
__device__ __forceinline__ void gl_lds16(const u16* g, u16* l) {
    __builtin_amdgcn_global_load_lds((const __attribute__((address_space(1))) unsigned int*)g,
                                     (__attribute__((address_space(3))) unsigned int*)l, 16, 0, 0);
}

// ---- one-shot f32 -> bf16 conversion of x + 4 weights -------------------
__global__ __launch_bounds__(256) void convert_all(const float* __restrict__ x,
                                                   const float* __restrict__ wq,
                                                   const float* __restrict__ wk,
                                                   const float* __restrict__ wv,
                                                   const float* __restrict__ wo,
                                                   u16* xb, u16* wqb, u16* wkb, u16* wvb, u16* wob) {
    size_t i8 = ((size_t)blockIdx.x * 256 + threadIdx.x) * 8;
    const float* src; u16* dst; size_t off;
    if (i8 < 8388608) { src = x; dst = xb; off = i8; }
    else {
        size_t idx = i8 - 8388608;
        int w = (int)(idx >> 20); off = idx & 1048575;
        src = (w == 0) ? wq : (w == 1) ? wk : (w == 2) ? wv : wo;
        dst = (w == 0) ? wqb : (w == 1) ? wkb : (w == 2) ? wvb : wob;
    }
    float4 a = *(const float4*)&src[off];
    float4 b = *(const float4*)&src[off + 4];
    *(uint4*)&dst[off] = pack8(a, b);
}

// ---- 128x128-tile bf16 GEMM core, BK=32 double-buffered prefetch --------
// acc = A(m0..+127, :) * B(n0..+127, :)^T, K=1024.
// LDS: per operand 2 buffers of 128x32 (8 KB) -> 32 KB total (same as BK=64
// single-buffer). Loop: barrier -> prefetch kt+1 (DMA flies over compute)
// -> compute kt. Swizzle: col-group ^ ((row>>1)&3) => quad-group
// ds_read_b128 is 2-way bank-aliased (free).
__device__ __forceinline__ void gemm_core(const u16* __restrict__ A, const u16* __restrict__ B,
                                          int m0, int n0, u16* As, u16* Bs, f32x4 acc[4][4]) {
    const int tid = threadIdx.x;
    const int wv = tid >> 6, lane = tid & 63, lr = lane & 15, quad = lane >> 4;
    const int lr4 = lane >> 2;               // 0..15 row offset within a 16-row group
    const int lc4 = lane & 3;                // col-chunk 0..3
    const int wm = (wv >> 1) * 64, wn = (wv & 1) * 64;
    const int rb0 = wv * 32, rb1 = wv * 32 + 16;   // this wave's staging row-groups

    // stage K-chunk 0 into buffer 0
    {
        int g0 = rb0 + lr4, g1 = rb1 + lr4;
        int c0 = lc4 ^ ((g0 >> 1) & 3), c1 = lc4 ^ ((g1 >> 1) & 3);
        gl_lds16(&A[(size_t)(m0 + g0) * 1024 + c0 * 8], &As[rb0 * 32]);
        gl_lds16(&A[(size_t)(m0 + g1) * 1024 + c1 * 8], &As[rb1 * 32]);
        gl_lds16(&B[(size_t)(n0 + g0) * 1024 + c0 * 8], &Bs[rb0 * 32]);
        gl_lds16(&B[(size_t)(n0 + g1) * 1024 + c1 * 8], &Bs[rb1 * 32]);
    }

    const int fsw = (quad ^ ((lr >> 1) & 3)) * 8;   // fragment-read swizzle offset

    for (int ki = 0; ki < 32; ++ki) {
        const int bo = (ki & 1) * 4096;             // current buffer offset (u16)
        __syncthreads();                            // staged chunk ki is ready
        if (ki < 31) {                              // prefetch ki+1 into idle buffer
            const int nbo = (bo ^ 4096);
            const int kt = (ki + 1) * 32;
            int g0 = rb0 + lr4, g1 = rb1 + lr4;
            int c0 = lc4 ^ ((g0 >> 1) & 3), c1 = lc4 ^ ((g1 >> 1) & 3);
            gl_lds16(&A[(size_t)(m0 + g0) * 1024 + kt + c0 * 8], &As[nbo + rb0 * 32]);
            gl_lds16(&A[(size_t)(m0 + g1) * 1024 + kt + c1 * 8], &As[nbo + rb1 * 32]);
            gl_lds16(&B[(size_t)(n0 + g0) * 1024 + kt + c0 * 8], &Bs[nbo + rb0 * 32]);
            gl_lds16(&B[(size_t)(n0 + g1) * 1024 + kt + c1 * 8], &Bs[nbo + rb1 * 32]);
        }
        short8 af[4], bf[4];
        #pragma unroll
        for (int mi = 0; mi < 4; ++mi)
            af[mi] = *(const short8*)&As[bo + (wm + mi * 16 + lr) * 32 + fsw];
        #pragma unroll
        for (int ni = 0; ni < 4; ++ni)
            bf[ni] = *(const short8*)&Bs[bo + (wn + ni * 16 + lr) * 32 + fsw];
        #pragma unroll
        for (int mi = 0; mi < 4; ++mi)
            #pragma unroll
            for (int ni = 0; ni < 4; ++ni)
                acc[mi][ni] = __builtin_amdgcn_mfma_f32_16x16x32_bf16(af[mi], bf[ni], acc[mi][ni], 0, 0, 0);
    }
}

// ---- fused QKV projection: z=0 Q (scaled by 0.125*log2e), z=1 K, z=2 V^T ----
__global__ __launch_bounds__(256) void gemm_qkv(const u16* __restrict__ xb,
                                                const u16* __restrict__ wq,
                                                const u16* __restrict__ wk,
                                                const u16* __restrict__ wv,
                                                u16* __restrict__ Qb, u16* __restrict__ Kb,
                                                u16* __restrict__ Vtb) {
    __shared__ __align__(16) u16 As[8192];   // 2 x (128x32)
    __shared__ __align__(16) u16 Bs[8192];
    const int z = blockIdx.z;
    const u16* A; const u16* B; int m0, n0;
    if (z == 2) { A = wv; B = xb; m0 = blockIdx.x * 128; n0 = blockIdx.y * 128; }
    else        { A = xb; B = (z ? wk : wq); m0 = blockIdx.y * 128; n0 = blockIdx.x * 128; }

    f32x4 acc[4][4];
    #pragma unroll
    for (int i = 0; i < 4; ++i)
        #pragma unroll
        for (int j = 0; j < 4; ++j) acc[i][j] = 0;

    gemm_core(A, B, m0, n0, As, Bs, acc);

    const int lane = threadIdx.x & 63, lr = lane & 15, quad = lane >> 4;
    const int wv4 = threadIdx.x >> 6;
    const int wm = (wv4 >> 1) * 64, wn = (wv4 & 1) * 64;
    const float scale = (z == 0) ? 0.18033688f : 1.0f;   // 0.125 * log2(e) for Q
    #pragma unroll
    for (int mi = 0; mi < 4; ++mi)
        #pragma unroll
        for (int ni = 0; ni < 4; ++ni)
            #pragma unroll
            for (int reg = 0; reg < 4; ++reg) {
                int row = m0 + wm + mi * 16 + quad * 4 + reg;
                int col = n0 + wn + ni * 16 + lr;
                u16 bv = f2bf(acc[mi][ni][reg] * scale);
                if (z == 2) {
                    int bhh = (col >> 11) * 16 + (row >> 6);
                    Vtb[(size_t)bhh * 131072 + (size_t)(row & 63) * 2048 + (col & 2047)] = bv;
                } else {
                    int bhh = (row >> 11) * 16 + (col >> 6);
                    (z ? Kb : Qb)[(size_t)bhh * 131072 + (size_t)(row & 2047) * 64 + (col & 63)] = bv;
                }
            }
}

// ---- output projection: C_f32 = Ob * Wo^T ------------------------------
__global__ __launch_bounds__(256) void gemm_out(const u16* __restrict__ Ob,
                                                const u16* __restrict__ wo,
                                                float* __restrict__ C) {
    __shared__ __align__(16) u16 As[8192];
    __shared__ __align__(16) u16 Bs[8192];
    const int m0 = blockIdx.y * 128, n0 = blockIdx.x * 128;

    f32x4 acc[4][4];
    #pragma unroll
    for (int i = 0; i < 4; ++i)
        #pragma unroll
        for (int j = 0; j < 4; ++j) acc[i][j] = 0;

    gemm_core(Ob, wo, m0, n0, As, Bs, acc);

    const int lane = threadIdx.x & 63, lr = lane & 15, quad = lane >> 4;
    const int wv4 = threadIdx.x >> 6;
    const int wm = (wv4 >> 1) * 64, wn = (wv4 & 1) * 64;
    #pragma unroll
    for (int mi = 0; mi < 4; ++mi)
        #pragma unroll
        for (int ni = 0; ni < 4; ++ni)
            #pragma unroll
            for (int reg = 0; reg < 4; ++reg) {
                int row = m0 + wm + mi * 16 + quad * 4 + reg;
                int col = n0 + wn + ni * 16 + lr;
                C[(size_t)row * 1024 + col] = acc[mi][ni][reg];
            }
}

// ---- block-cooperative flash attention, 8 waves (256 q-rows) per block --
// (unchanged from round 7)
__global__ __launch_bounds__(512, 4) void attn_flash(const u16* __restrict__ Q,
                                                     const u16* __restrict__ K,
                                                     const u16* __restrict__ Vt,
                                                     u16* __restrict__ O) {
    __shared__ __align__(16) u16 Kbuf[2][4096];    // 64 keys x 64 d, swizzled
    __shared__ __align__(16) u16 Vbuf[2][4096];    // 64 d x 64 keys, swizzled
    __shared__ __align__(16) u16 Ps[8][2048];      // per-wave P (32 q x 64 k), swizzled

    const int tid = threadIdx.x, wave = tid >> 6, lane = tid & 63;
    const int lr = lane & 15, quad = lane >> 4;
    const int bh = blockIdx.x & 63;                // bh%8 pinned -> XCD-local K/V in L2
    const int p  = blockIdx.x >> 6;                // 0..7
    const int qt8 = (p < 4) ? (7 - p) : (p - 4);   // first half heavy, second light
    const int qbase = qt8 * 256 + wave * 32;
    const size_t base = (size_t)bh * 131072;

    const int srow = lane >> 3;                    // 0..7
    const int scg  = (lane & 7) ^ srow;            // swizzled col-group

    const short8 onesv = {0x3f80, 0x3f80, 0x3f80, 0x3f80, 0x3f80, 0x3f80, 0x3f80, 0x3f80};

    short8 qf[2][2];
    #pragma unroll
    for (int qmi = 0; qmi < 2; ++qmi)
        #pragma unroll
        for (int c = 0; c < 2; ++c)
            qf[qmi][c] = *(const short8*)&Q[base + (size_t)(qbase + qmi * 16 + lr) * 64 + c * 32 + quad * 8];

    f32x4 oacc[4][2];
    #pragma unroll
    for (int i = 0; i < 4; ++i) { oacc[i][0] = 0; oacc[i][1] = 0; }
    f32x4 lacc[2];
    lacc[0] = 0; lacc[1] = 0;

    const int jmax = 4 * qt8 + 3;
    const int r0 = wave * 8;

    gl_lds16(&K[base + (size_t)(r0 + srow) * 64 + scg * 8], &Kbuf[0][r0 * 64]);
    gl_lds16(&Vt[base + (size_t)(r0 + srow) * 2048 + scg * 8], &Vbuf[0][r0 * 64]);

    for (int j = 0; j <= jmax; ++j) {
        const int buf = j & 1;
        __syncthreads();
        if (j < jmax) {
            const int nb = buf ^ 1;
            gl_lds16(&K[base + (size_t)((j + 1) * 64 + r0 + srow) * 64 + scg * 8], &Kbuf[nb][r0 * 64]);
            gl_lds16(&Vt[base + (size_t)(r0 + srow) * 2048 + (j + 1) * 64 + scg * 8], &Vbuf[nb][r0 * 64]);
        }

        if (j * 64 <= qbase + 31) {
            f32x4 st[4][2];
            #pragma unroll
            for (int ni = 0; ni < 4; ++ni) { st[ni][0] = 0; st[ni][1] = 0; }
            #pragma unroll
            for (int c = 0; c < 2; ++c) {
                short8 kf[4];
                #pragma unroll
                for (int ni = 0; ni < 4; ++ni)
                    kf[ni] = *(const short8*)&Kbuf[buf][(ni * 16 + lr) * 64 + (((c * 4 + quad) ^ (lr & 7)) * 8)];
                #pragma unroll
                for (int ni = 0; ni < 4; ++ni)
                    #pragma unroll
                    for (int qmi = 0; qmi < 2; ++qmi)
                        st[ni][qmi] = __builtin_amdgcn_mfma_f32_16x16x32_bf16(kf[ni], qf[qmi][c], st[ni][qmi], 0, 0, 0);
            }

            if (j >= 4 * qt8) {
                #pragma unroll
                for (int ni = 0; ni < 4; ++ni)
                    #pragma unroll
                    for (int qmi = 0; qmi < 2; ++qmi)
                        #pragma unroll
                        for (int reg = 0; reg < 4; ++reg) {
                            int key = j * 64 + ni * 16 + quad * 4 + reg;
                            int q   = qbase + qmi * 16 + lr;
                            if (key > q) st[ni][qmi][reg] = -3.0e38f;   // exp2 -> 0
                        }
            }

            #pragma unroll
            for (int qmi = 0; qmi < 2; ++qmi) {
                #pragma unroll
                for (int ni = 0; ni < 4; ++ni) {
                    unsigned u0 = __float_as_uint(exp2f(st[ni][qmi][0]));
                    unsigned u1 = __float_as_uint(exp2f(st[ni][qmi][1]));
                    unsigned u2 = __float_as_uint(exp2f(st[ni][qmi][2]));
                    unsigned u3 = __float_as_uint(exp2f(st[ni][qmi][3]));
                    uint2 pk;
                    pk.x = __builtin_amdgcn_perm(u1, u0, 0x07060302);
                    pk.y = __builtin_amdgcn_perm(u3, u2, 0x07060302);
                    int g8 = ni * 2 + (quad >> 1);
                    *(uint2*)&Ps[wave][qmi * 1024 + lr * 64 + ((g8 ^ (lr & 7)) * 8 + (quad & 1) * 4)] = pk;
                }
            }

            #pragma unroll
            for (int c = 0; c < 2; ++c) {
                short8 pf[2];
                #pragma unroll
                for (int qmi = 0; qmi < 2; ++qmi)
                    pf[qmi] = *(const short8*)&Ps[wave][qmi * 1024 + lr * 64 + (((c * 4 + quad) ^ (lr & 7)) * 8)];
                #pragma unroll
                for (int dmi = 0; dmi < 4; ++dmi) {
                    short8 vf = *(const short8*)&Vbuf[buf][(dmi * 16 + lr) * 64 + (((c * 4 + quad) ^ (lr & 7)) * 8)];
                    #pragma unroll
                    for (int qmi = 0; qmi < 2; ++qmi)
                        oacc[dmi][qmi] = __builtin_amdgcn_mfma_f32_16x16x32_bf16(vf, pf[qmi], oacc[dmi][qmi], 0, 0, 0);
                }
                #pragma unroll
                for (int qmi = 0; qmi < 2; ++qmi)
                    lacc[qmi] = __builtin_amdgcn_mfma_f32_16x16x32_bf16(onesv, pf[qmi], lacc[qmi], 0, 0, 0);
            }
        }
    }

    const int b = bh >> 4, h = bh & 15;
    #pragma unroll
    for (int qmi = 0; qmi < 2; ++qmi) {
        float rl = 1.0f / lacc[qmi][0];
        int s = qbase + qmi * 16 + lr;
        #pragma unroll
        for (int dmi = 0; dmi < 4; ++dmi) {
            unsigned o0 = f2bf(oacc[dmi][qmi][0] * rl);
            unsigned o1 = f2bf(oacc[dmi][qmi][1] * rl);
            unsigned o2 = f2bf(oacc[dmi][qmi][2] * rl);
            unsigned o3 = f2bf(oacc[dmi][qmi][3] * rl);
            uint2 pk;
            pk.x = o0 | (o1 << 16);
            pk.y = o2 | (o3 << 16);
            *(uint2*)&O[((size_t)(b * 2048 + s)) * 1024 + h * 64 + dmi * 16 + quad * 4] = pk;
        }
    }
}

extern "C" void kernel_launch(void* const* d_in, const int* in_sizes, int n_in,
                              void* d_out, int out_size, void* d_ws, size_t ws_size,
                              hipStream_t stream) {
    const float* x  = (const float*)d_in[0];
    const float* Wq = (const float*)d_in[1];
    const float* Wk = (const float*)d_in[2];
    const float* Wv = (const float*)d_in[3];
    const float* Wo = (const float*)d_in[4];

    u16* xb  = (u16*)d_ws;
    u16* wqb = xb + 8388608;
    u16* wkb = wqb + 1048576;
    u16* wvb = wkb + 1048576;
    u16* wob = wvb + 1048576;
    u16* Qb  = wob + 1048576;
    u16* Kb  = Qb + 8388608;
    u16* Vtb = Kb + 8388608;
    u16* Ob  = xb;   // alias: x dead after gemm_qkv

    convert_all<<<6144, 256, 0, stream>>>(x, Wq, Wk, Wv, Wo, xb, wqb, wkb, wvb, wob);

    gemm_qkv<<<dim3(8, 64, 3), 256, 0, stream>>>(xb, wqb, wkb, wvb, Qb, Kb, Vtb);

    attn_flash<<<512, 512, 0, stream>>>(Qb, Kb, Vtb, Ob);

    gemm_out<<<dim3(8, 64), 256, 0, stream>>>(Ob, wob, (float*)d_out);
}